// Round 2
// baseline (1316.545 us; speedup 1.0000x reference)
//
#include <hip/hip_runtime.h>
#include <hip/hip_bf16.h>

typedef __bf16 bf16x8 __attribute__((ext_vector_type(8)));
typedef float  f32x4  __attribute__((ext_vector_type(4)));

#define MFMA16(a, b, c) __builtin_amdgcn_mfma_f32_16x16x32_bf16((a), (b), (c), 0, 0, 0)

// fp32 weights -> bf16 copies in workspace (re-done every launch; no static
// state). n-major ([out][in]) so a lane's 8 k-elements = 16 contiguous bytes.
__global__ void prep_weights(const float* __restrict__ W1, const float* __restrict__ W2,
                             const float* __restrict__ Wf1, const float* __restrict__ Wf2,
                             __bf16* __restrict__ w1b, __bf16* __restrict__ w2b,
                             __bf16* __restrict__ wf1b, __bf16* __restrict__ wf2b) {
    int i = blockIdx.x * 256 + threadIdx.x;
    if (i < 256 * 512) w1b[i]  = (__bf16)W1[i];
    if (i < 128 * 256) w2b[i]  = (__bf16)W2[i];
    if (i < 64 * 128)  wf1b[i] = (__bf16)Wf1[i];
    if (i < 2 * 64)    wf2b[i] = (__bf16)Wf2[i];
}

// One wave owns 16 rows end-to-end. 16 rows (not 32) keeps the layer-1
// accumulator at 64 VGPRs -> ~110 total -> 4 waves/SIMD; LDS 33792 B/block
// (4 waves) -> 4 blocks/CU -> 16 waves/CU (50% occupancy) vs 8 before.
// X loads are software-pipelined depth-2; a raw s_barrier (no memory
// semantics) keeps the block's 4 waves streaming the same weight slice so
// the per-CU L1 serves 3 of 4 waves.
// MFMA 16x16x32 bf16 layouts (verified):
//   A[m = lane&15][k = (lane>>4)*8 + j]
//   B[k = (lane>>4)*8 + j][n = lane&15]   (n-major weight rows -> 16B/lane)
//   C/D: col = lane&15, row = (lane>>4)*4 + reg
__global__ __launch_bounds__(256, 4)
void mlp_kernel(const float* __restrict__ X,
                const __bf16* __restrict__ w1b,  const float* __restrict__ b1,
                const __bf16* __restrict__ w2b,  const float* __restrict__ b2,
                const __bf16* __restrict__ wf1b, const float* __restrict__ bf1,
                const __bf16* __restrict__ wf2b, const float* __restrict__ bf2,
                float* __restrict__ out) {
    // stride 264 bf16 = 528 B: 16B-aligned rows, row stride == 4 banks mod 32
    // -> b128 A-reads are bank-balanced (8 words/bank, the b128 minimum).
    __shared__ __align__(16) __bf16 hbuf[4][16][264];

    const int lane = threadIdx.x & 63;
    const int wave = threadIdx.x >> 6;
    const int m16  = lane & 15;
    const int q    = lane >> 4;
    const int row0 = blockIdx.x * 64 + wave * 16;
    __bf16(*hw)[264] = hbuf[wave];

    // ---------------- Layer 1: h1[16,256] = relu(X[16,512] @ W1^T + b1) ----
    f32x4 C1[16];
#pragma unroll
    for (int ct = 0; ct < 16; ++ct) C1[ct] = (f32x4){0.f, 0.f, 0.f, 0.f};

    const float* xr = X + (size_t)(row0 + m16) * 512 + q * 8;
    float4 pa[2], pb[2];
    pa[0] = *(const float4*)(xr +  0);
    pb[0] = *(const float4*)(xr +  4);
    pa[1] = *(const float4*)(xr + 32);
    pb[1] = *(const float4*)(xr + 36);

#pragma unroll
    for (int ks = 0; ks < 16; ++ks) {
        __builtin_amdgcn_s_barrier();  // align waves -> shared L1 weight slice
        float4 c0 = pa[ks & 1], c1 = pb[ks & 1];
        if (ks < 14) {  // prefetch ks+2 (in flight across 2 iterations)
            pa[ks & 1] = *(const float4*)(xr + (ks + 2) * 32);
            pb[ks & 1] = *(const float4*)(xr + (ks + 2) * 32 + 4);
        }
        bf16x8 a;
        a[0] = (__bf16)c0.x; a[1] = (__bf16)c0.y;
        a[2] = (__bf16)c0.z; a[3] = (__bf16)c0.w;
        a[4] = (__bf16)c1.x; a[5] = (__bf16)c1.y;
        a[6] = (__bf16)c1.z; a[7] = (__bf16)c1.w;

        const __bf16* wp = w1b + (size_t)m16 * 512 + ks * 32 + q * 8;
#pragma unroll
        for (int ct = 0; ct < 16; ++ct) {
            bf16x8 b = *(const bf16x8*)(wp + (size_t)ct * 16 * 512);
            C1[ct] = MFMA16(a, b, C1[ct]);
        }
    }
#pragma unroll
    for (int ct = 0; ct < 16; ++ct) {
        float bias = b1[ct * 16 + m16];
#pragma unroll
        for (int r = 0; r < 4; ++r) {
            float v = C1[ct][r] + bias;
            v = v > 0.f ? v : 0.f;
            hw[q * 4 + r][ct * 16 + m16] = (__bf16)v;
        }
    }

    // ---------------- Layer 2: h2[16,128] = relu(h1 @ W2^T + b2) -----------
    f32x4 C2[8];
#pragma unroll
    for (int ct = 0; ct < 8; ++ct) C2[ct] = (f32x4){0.f, 0.f, 0.f, 0.f};

#pragma unroll
    for (int ks = 0; ks < 8; ++ks) {
        __builtin_amdgcn_s_barrier();
        bf16x8 a = *(const bf16x8*)&hw[m16][ks * 32 + q * 8];
        const __bf16* wp = w2b + (size_t)m16 * 256 + ks * 32 + q * 8;
#pragma unroll
        for (int ct = 0; ct < 8; ++ct) {
            bf16x8 b = *(const bf16x8*)(wp + (size_t)ct * 16 * 256);
            C2[ct] = MFMA16(a, b, C2[ct]);
        }
    }
#pragma unroll
    for (int ct = 0; ct < 8; ++ct) {
        float bias = b2[ct * 16 + m16];
#pragma unroll
        for (int r = 0; r < 4; ++r) {
            float v = C2[ct][r] + bias;
            v = v > 0.f ? v : 0.f;
            hw[q * 4 + r][ct * 16 + m16] = (__bf16)v;
        }
    }

    // ---------------- Layer 3: h3[16,64] = relu(h2 @ Wf1^T + bf1) ----------
    f32x4 C3[4];
#pragma unroll
    for (int ct = 0; ct < 4; ++ct) C3[ct] = (f32x4){0.f, 0.f, 0.f, 0.f};

#pragma unroll
    for (int ks = 0; ks < 4; ++ks) {
        bf16x8 a = *(const bf16x8*)&hw[m16][ks * 32 + q * 8];
        const __bf16* wp = wf1b + (size_t)m16 * 128 + ks * 32 + q * 8;
#pragma unroll
        for (int ct = 0; ct < 4; ++ct) {
            bf16x8 b = *(const bf16x8*)(wp + (size_t)ct * 16 * 128);
            C3[ct] = MFMA16(a, b, C3[ct]);
        }
    }
#pragma unroll
    for (int ct = 0; ct < 4; ++ct) {
        float bias = bf1[ct * 16 + m16];
#pragma unroll
        for (int r = 0; r < 4; ++r) {
            float v = C3[ct][r] + bias;
            v = v > 0.f ? v : 0.f;
            hw[q * 4 + r][ct * 16 + m16] = (__bf16)v;
        }
    }

    // ---------------- Layer 4 + softmax (fp32) -----------------------------
    {
        const int r = (lane >> 1) & 15;  // all lanes compute; lanes<32 store
        const int c = lane & 1;
        float dot = 0.f;
#pragma unroll
        for (int j8 = 0; j8 < 8; ++j8) {
            bf16x8 hv = *(const bf16x8*)&hw[r][j8 * 8];
            bf16x8 wv = *(const bf16x8*)(wf2b + c * 64 + j8 * 8);
#pragma unroll
            for (int j = 0; j < 8; ++j) dot += (float)hv[j] * (float)wv[j];
        }
        float logit = dot + bf2[c];
        float other = __shfl_xor(logit, 1, 64);
        float mx = fmaxf(logit, other);
        float e0 = expf(logit - mx);
        float e1 = expf(other - mx);
        if (lane < 32) out[(size_t)(row0 + r) * 2 + c] = e0 / (e0 + e1);
    }
}

extern "C" void kernel_launch(void* const* d_in, const int* in_sizes, int n_in,
                              void* d_out, int out_size, void* d_ws, size_t ws_size,
                              hipStream_t stream) {
    const float* X   = (const float*)d_in[0];
    const float* W1  = (const float*)d_in[1];
    const float* b1  = (const float*)d_in[2];
    const float* W2  = (const float*)d_in[3];
    const float* b2  = (const float*)d_in[4];
    const float* Wf1 = (const float*)d_in[5];
    const float* bf1 = (const float*)d_in[6];
    const float* Wf2 = (const float*)d_in[7];
    const float* bf2 = (const float*)d_in[8];
    float* out = (float*)d_out;

    const int N = in_sizes[0] / 512;  // 262144

    __bf16* w1b  = (__bf16*)d_ws;           // 256*512
    __bf16* w2b  = w1b + 256 * 512;         // 128*256
    __bf16* wf1b = w2b + 128 * 256;         // 64*128
    __bf16* wf2b = wf1b + 64 * 128;         // 2*64

    prep_weights<<<512, 256, 0, stream>>>(W1, W2, Wf1, Wf2, w1b, w2b, wf1b, wf2b);
    mlp_kernel<<<N / 64, 256, 0, stream>>>(X, w1b, b1, w2b, b2, wf1b, bf1,
                                           wf2b, bf2, out);
}

// Round 3
// 799.509 us; speedup vs baseline: 1.6467x; 1.6467x over previous
//
#include <hip/hip_runtime.h>
#include <hip/hip_bf16.h>

typedef __bf16 bf16x8 __attribute__((ext_vector_type(8)));
typedef float  f32x4  __attribute__((ext_vector_type(4)));

#define MFMA16(a, b, c) __builtin_amdgcn_mfma_f32_16x16x32_bf16((a), (b), (c), 0, 0, 0)

// Pack weights into MFMA-B-fragment order so one wave b-load = 1 KB coalesced:
//   wp[((ks*CT + ct)*64 + lane)*8 + j] = W[(ct*16 + (lane&15))*K + ks*32 + (lane>>4)*8 + j]
// (lane = q*16+m16 holds B[k=q*8+j][n=m16] for col-tile ct, k-tile ks.)
__global__ void prep_weights(const float* __restrict__ W1, const float* __restrict__ W2,
                             const float* __restrict__ Wf1, const float* __restrict__ Wf2,
                             __bf16* __restrict__ w1p, __bf16* __restrict__ w2p,
                             __bf16* __restrict__ wf1p, __bf16* __restrict__ wf2b) {
    int t = blockIdx.x * 256 + threadIdx.x;
    int lane = t & 63, m16 = lane & 15, q = (lane >> 4) & 3;
    if (t < 16384) {  // W1: K=512, CT=16
        int ct = (t >> 6) & 15, ks = t >> 10;
        const float* s = W1 + (size_t)(ct * 16 + m16) * 512 + ks * 32 + q * 8;
        __bf16* d = w1p + (size_t)t * 8;
        for (int j = 0; j < 8; ++j) d[j] = (__bf16)s[j];
    }
    if (t < 4096) {   // W2: K=256, CT=8
        int ct = (t >> 6) & 7, ks = t >> 9;
        const float* s = W2 + (size_t)(ct * 16 + m16) * 256 + ks * 32 + q * 8;
        __bf16* d = w2p + (size_t)t * 8;
        for (int j = 0; j < 8; ++j) d[j] = (__bf16)s[j];
    }
    if (t < 1024) {   // Wf1: K=128, CT=4
        int ct = (t >> 6) & 3, ks = t >> 8;
        const float* s = Wf1 + (size_t)(ct * 16 + m16) * 128 + ks * 32 + q * 8;
        __bf16* d = wf1p + (size_t)t * 8;
        for (int j = 0; j < 8; ++j) d[j] = (__bf16)s[j];
    }
    if (t < 128) wf2b[t] = (__bf16)Wf2[t];
}

// One wave owns 32 rows end-to-end; 128-thread blocks; launch_bounds(128,2)
// -> 256-VGPR budget (R1-proven no-spill regime; R2's (256,4) spilled 355 MB).
// Weight loads are fragment-packed (1 KB coalesced per wave), batched 8 at a
// time and double-buffered across the 32 MFMAs of each K-step; X is
// depth-1 prefetched. No __syncthreads anywhere (h is wave-private LDS).
__global__ __launch_bounds__(128, 2)
void mlp_kernel(const float* __restrict__ X,
                const __bf16* __restrict__ w1p,  const float* __restrict__ b1,
                const __bf16* __restrict__ w2p,  const float* __restrict__ b2,
                const __bf16* __restrict__ wf1p, const float* __restrict__ bf1,
                const __bf16* __restrict__ wf2b, const float* __restrict__ bf2,
                float* __restrict__ out) {
    // stride 264 bf16 = 528 B: 16B-aligned rows; read start-banks spread
    // 4*(m16+q) mod 32 -> balanced 8 words/bank (minimum) for b128 reads.
    __shared__ __align__(16) __bf16 hbuf[2][32][264];

    const int lane = threadIdx.x & 63;
    const int wave = threadIdx.x >> 6;
    const int m16  = lane & 15;
    const int q    = lane >> 4;
    const int row0 = blockIdx.x * 64 + wave * 32;
    __bf16(*hw)[264] = hbuf[wave];

    // ---------------- Layer 1: h1[32,256] = relu(X[32,512] @ W1^T + b1) ----
    f32x4 C1[2][16];
#pragma unroll
    for (int rt = 0; rt < 2; ++rt)
#pragma unroll
        for (int ct = 0; ct < 16; ++ct) C1[rt][ct] = (f32x4){0.f, 0.f, 0.f, 0.f};

    const float* xr0 = X + (size_t)(row0 + m16) * 512 + q * 8;
    const float* xr1 = xr0 + (size_t)16 * 512;
    float4 x00 = *(const float4*)(xr0);
    float4 x01 = *(const float4*)(xr0 + 4);
    float4 x10 = *(const float4*)(xr1);
    float4 x11 = *(const float4*)(xr1 + 4);

#pragma unroll
    for (int ks = 0; ks < 16; ++ks) {
        const __bf16* wp = w1p + (size_t)ks * 8192 + lane * 8;
        bf16x8 b0[8], b1v[8];
#pragma unroll
        for (int ct = 0; ct < 8; ++ct)       // batch 0: 1 KB coalesced each
            b0[ct] = *(const bf16x8*)(wp + ct * 512);

        bf16x8 a0, a1;
        a0[0] = (__bf16)x00.x; a0[1] = (__bf16)x00.y; a0[2] = (__bf16)x00.z; a0[3] = (__bf16)x00.w;
        a0[4] = (__bf16)x01.x; a0[5] = (__bf16)x01.y; a0[6] = (__bf16)x01.z; a0[7] = (__bf16)x01.w;
        a1[0] = (__bf16)x10.x; a1[1] = (__bf16)x10.y; a1[2] = (__bf16)x10.z; a1[3] = (__bf16)x10.w;
        a1[4] = (__bf16)x11.x; a1[5] = (__bf16)x11.y; a1[6] = (__bf16)x11.z; a1[7] = (__bf16)x11.w;

        if (ks < 15) {  // depth-1 X prefetch: lands during the 32 MFMAs below
            x00 = *(const float4*)(xr0 + (ks + 1) * 32);
            x01 = *(const float4*)(xr0 + (ks + 1) * 32 + 4);
            x10 = *(const float4*)(xr1 + (ks + 1) * 32);
            x11 = *(const float4*)(xr1 + (ks + 1) * 32 + 4);
        }
#pragma unroll
        for (int ct = 0; ct < 8; ++ct)       // batch 1 in flight over batch-0 MFMAs
            b1v[ct] = *(const bf16x8*)(wp + (8 + ct) * 512);

#pragma unroll
        for (int ct = 0; ct < 8; ++ct) {
            C1[0][ct] = MFMA16(a0, b0[ct], C1[0][ct]);
            C1[1][ct] = MFMA16(a1, b0[ct], C1[1][ct]);
        }
#pragma unroll
        for (int ct = 0; ct < 8; ++ct) {
            C1[0][8 + ct] = MFMA16(a0, b1v[ct], C1[0][8 + ct]);
            C1[1][8 + ct] = MFMA16(a1, b1v[ct], C1[1][8 + ct]);
        }
    }
#pragma unroll
    for (int ct = 0; ct < 16; ++ct) {
        float bias = b1[ct * 16 + m16];
#pragma unroll
        for (int rt = 0; rt < 2; ++rt)
#pragma unroll
            for (int r = 0; r < 4; ++r) {
                float v = C1[rt][ct][r] + bias;
                v = v > 0.f ? v : 0.f;
                hw[rt * 16 + q * 4 + r][ct * 16 + m16] = (__bf16)v;
            }
    }

    // ---------------- Layer 2: h2[32,128] = relu(h1 @ W2^T + b2) -----------
    f32x4 C2[2][8];
#pragma unroll
    for (int rt = 0; rt < 2; ++rt)
#pragma unroll
        for (int ct = 0; ct < 8; ++ct) C2[rt][ct] = (f32x4){0.f, 0.f, 0.f, 0.f};

#pragma unroll
    for (int ks = 0; ks < 8; ++ks) {
        const __bf16* wp = w2p + (size_t)ks * 4096 + lane * 8;
        bf16x8 b[8];
#pragma unroll
        for (int ct = 0; ct < 8; ++ct) b[ct] = *(const bf16x8*)(wp + ct * 512);
        bf16x8 a0 = *(const bf16x8*)&hw[m16][ks * 32 + q * 8];
        bf16x8 a1 = *(const bf16x8*)&hw[16 + m16][ks * 32 + q * 8];
#pragma unroll
        for (int ct = 0; ct < 8; ++ct) {
            C2[0][ct] = MFMA16(a0, b[ct], C2[0][ct]);
            C2[1][ct] = MFMA16(a1, b[ct], C2[1][ct]);
        }
    }
#pragma unroll
    for (int ct = 0; ct < 8; ++ct) {
        float bias = b2[ct * 16 + m16];
#pragma unroll
        for (int rt = 0; rt < 2; ++rt)
#pragma unroll
            for (int r = 0; r < 4; ++r) {
                float v = C2[rt][ct][r] + bias;
                v = v > 0.f ? v : 0.f;
                hw[rt * 16 + q * 4 + r][ct * 16 + m16] = (__bf16)v;
            }
    }

    // ---------------- Layer 3: h3[32,64] = relu(h2 @ Wf1^T + bf1) ----------
    f32x4 C3[2][4];
#pragma unroll
    for (int rt = 0; rt < 2; ++rt)
#pragma unroll
        for (int ct = 0; ct < 4; ++ct) C3[rt][ct] = (f32x4){0.f, 0.f, 0.f, 0.f};

#pragma unroll
    for (int ks = 0; ks < 4; ++ks) {
        const __bf16* wp = wf1p + (size_t)ks * 2048 + lane * 8;
        bf16x8 b[4];
#pragma unroll
        for (int ct = 0; ct < 4; ++ct) b[ct] = *(const bf16x8*)(wp + ct * 512);
        bf16x8 a0 = *(const bf16x8*)&hw[m16][ks * 32 + q * 8];
        bf16x8 a1 = *(const bf16x8*)&hw[16 + m16][ks * 32 + q * 8];
#pragma unroll
        for (int ct = 0; ct < 4; ++ct) {
            C3[0][ct] = MFMA16(a0, b[ct], C3[0][ct]);
            C3[1][ct] = MFMA16(a1, b[ct], C3[1][ct]);
        }
    }
#pragma unroll
    for (int ct = 0; ct < 4; ++ct) {
        float bias = bf1[ct * 16 + m16];
#pragma unroll
        for (int rt = 0; rt < 2; ++rt)
#pragma unroll
            for (int r = 0; r < 4; ++r) {
                float v = C3[rt][ct][r] + bias;
                v = v > 0.f ? v : 0.f;
                hw[rt * 16 + q * 4 + r][ct * 16 + m16] = (__bf16)v;
            }
    }

    // ---------------- Layer 4 + softmax (fp32): lane -> (row, class) -------
    {
        const int r = lane >> 1;   // 0..31
        const int c = lane & 1;
        float dot = 0.f;
#pragma unroll
        for (int j8 = 0; j8 < 8; ++j8) {
            bf16x8 hv = *(const bf16x8*)&hw[r][j8 * 8];
            bf16x8 wv = *(const bf16x8*)(wf2b + c * 64 + j8 * 8);
#pragma unroll
            for (int j = 0; j < 8; ++j) dot += (float)hv[j] * (float)wv[j];
        }
        float logit = dot + bf2[c];
        float other = __shfl_xor(logit, 1, 64);
        float mx = fmaxf(logit, other);
        float e0 = expf(logit - mx);
        float e1 = expf(other - mx);
        out[(size_t)(row0 + r) * 2 + c] = e0 / (e0 + e1);
    }
}

extern "C" void kernel_launch(void* const* d_in, const int* in_sizes, int n_in,
                              void* d_out, int out_size, void* d_ws, size_t ws_size,
                              hipStream_t stream) {
    const float* X   = (const float*)d_in[0];
    const float* W1  = (const float*)d_in[1];
    const float* b1  = (const float*)d_in[2];
    const float* W2  = (const float*)d_in[3];
    const float* b2  = (const float*)d_in[4];
    const float* Wf1 = (const float*)d_in[5];
    const float* bf1 = (const float*)d_in[6];
    const float* Wf2 = (const float*)d_in[7];
    const float* bf2 = (const float*)d_in[8];
    float* out = (float*)d_out;

    const int N = in_sizes[0] / 512;  // 262144

    __bf16* w1p  = (__bf16*)d_ws;            // 16384*8  = 131072 elems
    __bf16* w2p  = w1p  + 131072;            // 4096*8   = 32768
    __bf16* wf1p = w2p  + 32768;             // 1024*8   = 8192
    __bf16* wf2b = wf1p + 8192;              // 128

    prep_weights<<<64, 256, 0, stream>>>(W1, W2, Wf1, Wf2, w1p, w2p, wf1p, wf2b);
    mlp_kernel<<<N / 64, 128, 0, stream>>>(X, w1p, b1, w2p, b2, wf1p, bf1,
                                           wf2b, bf2, out);
}